// Round 2
// baseline (3591.107 us; speedup 1.0000x reference)
//
#include <hip/hip_runtime.h>

typedef unsigned short u16;
typedef unsigned int u32;
typedef unsigned long long u64;
typedef float f32x4 __attribute__((ext_vector_type(4)));
typedef short s16x8 __attribute__((ext_vector_type(8)));

__device__ inline float bf2f(u16 u){ return __uint_as_float(((u32)u) << 16); }
__device__ inline u16 f2bf(float x){
  u32 u = __float_as_uint(x);
  return (u16)((u + 0x7fffu + ((u >> 16) & 1u)) >> 16);
}
__device__ inline u32 pk2(float a, float b){ return (u32)f2bf(a) | ((u32)f2bf(b) << 16); }
__device__ inline float rcpf_(float x){ return __builtin_amdgcn_rcpf(x); }
__device__ inline float sigf(float x){ return rcpf_(1.f + __expf(-x)); }
__device__ inline float tanhf_(float x){
  float xx = fminf(15.f, fmaxf(-15.f, x));
  float e = __expf(2.f * xx);
  return (e - 1.f) * rcpf_(e + 1.f);
}
__device__ inline float ldf(const void* p, int i, bool f32){
  return f32 ? ((const float*)p)[i] : bf2f(((const u16*)p)[i]);
}
// load 8 contiguous values as bf16x8 (uint4), converting from f32 if needed
__device__ inline uint4 ld8(const void* base, size_t off, bool f32){
  if (f32){
    const float* p = (const float*)base + off;
    float4 a = *(const float4*)p;
    float4 b = *(const float4*)(p + 4);
    return make_uint4(pk2(a.x,a.y), pk2(a.z,a.w), pk2(b.x,b.y), pk2(b.z,b.w));
  }
  return *(const uint4*)((const u16*)base + off);
}

// ---------------------------------------------------------------------------
// Runtime dtype sniffer: bf16 data -> low u16 of each dword has a sane bf16
// exponent (~N(0,1)); f32 data -> low u16 is mantissa bits (uniform exponent).
// flag = 1 if inputs are float32, 0 if bf16.
// ---------------------------------------------------------------------------
__global__ void sniff_k(const u32* __restrict__ x1w, u32* __restrict__ flag){
  u32 v = x1w[threadIdx.x];
  u32 e = (v >> 7) & 0xffu;
  u64 m = __ballot(e >= 100u && e <= 140u);
  if (threadIdx.x == 0) *flag = (__popcll(m) >= 40) ? 0u : 1u;
}

// ---------------------------------------------------------------------------
// Generic 128x128-tile bf16 MFMA GEMM, C = A * B^T (+bias) with per-mode
// epilogue. MODE 0: XG = x1 @ [w_ih_f;w_ih_b]^T + (b_ih+b_hh), out bf16 s2048
//          MODE 1: x2h = X2C @ mlp_mha_w^T + b -> FIN[.,512+n] (bf16, s1024)
//          MODE 2: out = FIN @ mlp_w^T + mlp_b, masked by t<len, N=400
// A external (dtype-flagged) only in MODE 0; B/biases always external.
// ---------------------------------------------------------------------------
template<int MODE>
__global__ __launch_bounds__(256) void gemm_k(
    const void* A, const void* Bm0, const void* Bm1,
    const void* bias0, const void* bias1, const void* bias2, const void* bias3,
    void* Cout, const int* __restrict__ lens, const u32* __restrict__ flag)
{
  constexpr int KACT = (MODE == 2) ? 1024 : 400;
  constexpr int KT   = (MODE == 2) ? 32 : 13;
  constexpr int AS   = (MODE == 0) ? 400 : 1024;   // A row stride (elements)
  constexpr int BS   = (MODE == 2) ? 1024 : 400;   // B row stride (elements)

  const bool f32in = (*flag != 0);
  const bool aF32  = (MODE == 0) && f32in;

  __shared__ alignas(16) u16 Asl[2][128 * 40];
  __shared__ alignas(16) u16 Bsl[2][128 * 40];

  const int tid = threadIdx.x;
  const int m0 = blockIdx.x * 128, n0 = blockIdx.y * 128;
  const int lane = tid & 63, wv = tid >> 6, wm = wv >> 1, wn = wv & 1;

  uint4 ra[2], rb[2];

  auto load_tiles = [&](int kt){
    #pragma unroll
    for (int rep = 0; rep < 2; ++rep){
      int o = rep * 256 + tid;
      int row = o >> 2, oct = o & 3;
      int gc = kt * 32 + oct * 8;
      uint4 va = make_uint4(0,0,0,0), vb = make_uint4(0,0,0,0);
      if (gc < KACT){
        va = ld8(A, (size_t)(m0 + row) * AS + gc, aF32);
        int grow = n0 + row;
        if (MODE == 0){
          const void* bsrc; size_t boff;
          if (grow < 1024){ bsrc = Bm0; boff = (size_t)grow * 400 + gc; }
          else            { bsrc = Bm1; boff = (size_t)(grow - 1024) * 400 + gc; }
          vb = ld8(bsrc, boff, f32in);
        } else if (MODE == 1){
          vb = ld8(Bm0, (size_t)grow * 400 + gc, f32in);
        } else {
          if (grow < 400) vb = ld8(Bm0, (size_t)grow * 1024 + gc, f32in);
        }
      }
      ra[rep] = va; rb[rep] = vb;
    }
  };
  auto store_tiles = [&](int buf){
    #pragma unroll
    for (int rep = 0; rep < 2; ++rep){
      int o = rep * 256 + tid;
      int row = o >> 2, oct = o & 3;
      *(uint4*)(&Asl[buf][row * 40 + oct * 8]) = ra[rep];
      *(uint4*)(&Bsl[buf][row * 40 + oct * 8]) = rb[rep];
    }
  };

  f32x4 acc[4][4];
  #pragma unroll
  for (int mt = 0; mt < 4; ++mt)
    #pragma unroll
    for (int nt = 0; nt < 4; ++nt) acc[mt][nt] = f32x4{0.f,0.f,0.f,0.f};

  load_tiles(0);
  store_tiles(0);
  __syncthreads();

  for (int kt = 0; kt < KT; ++kt){
    if (kt + 1 < KT) load_tiles(kt + 1);
    int buf = kt & 1;
    s16x8 af[4], bfr[4];
    #pragma unroll
    for (int mt = 0; mt < 4; ++mt)
      af[mt] = *(const s16x8*)(&Asl[buf][(wm * 64 + mt * 16 + (lane & 15)) * 40 + (lane >> 4) * 8]);
    #pragma unroll
    for (int nt = 0; nt < 4; ++nt)
      bfr[nt] = *(const s16x8*)(&Bsl[buf][(wn * 64 + nt * 16 + (lane & 15)) * 40 + (lane >> 4) * 8]);
    #pragma unroll
    for (int mt = 0; mt < 4; ++mt)
      #pragma unroll
      for (int nt = 0; nt < 4; ++nt)
        acc[mt][nt] = __builtin_amdgcn_mfma_f32_16x16x32_bf16(af[mt], bfr[nt], acc[mt][nt], 0, 0, 0);
    if (kt + 1 < KT) store_tiles(buf ^ 1);
    __syncthreads();
  }

  #pragma unroll
  for (int nt = 0; nt < 4; ++nt){
    int n = n0 + wn * 64 + nt * 16 + (lane & 15);
    float bs = 0.f;
    if (MODE == 0) bs = (n < 1024) ? (ldf(bias0, n, f32in) + ldf(bias1, n, f32in))
                                   : (ldf(bias2, n - 1024, f32in) + ldf(bias3, n - 1024, f32in));
    if (MODE == 1) bs = ldf(bias0, n, f32in);
    if (MODE == 2) bs = (n < 400) ? ldf(bias0, n, f32in) : 0.f;
    #pragma unroll
    for (int mt = 0; mt < 4; ++mt){
      #pragma unroll
      for (int r = 0; r < 4; ++r){
        int m = m0 + wm * 64 + mt * 16 + (lane >> 4) * 4 + r;
        float v = acc[mt][nt][r] + bs;
        if (MODE == 0){
          ((u16*)Cout)[(size_t)m * 2048 + n] = f2bf(v);
        } else if (MODE == 1){
          ((u16*)Cout)[(size_t)m * 1024 + 512 + n] = f2bf(v);
        } else {
          if (n < 400){
            int b = m >> 10, t = m & 1023;
            float vv = (t < lens[b]) ? v : 0.f;
            if (f32in) ((float*)Cout)[(size_t)m * 400 + n] = vv;
            else       ((u16*)Cout)[(size_t)m * 400 + n] = f2bf(vv);
          }
        }
      }
    }
  }
}

// ---------------------------------------------------------------------------
// x2ctx[b,t,e] = mean_s x2[b,t,s,e]  (attention collapses analytically:
// softmax rows sum to 1 -> attn.mean(-1) = 1/S -> w = uniform 1/S).
// Output into FIN cols 0..399 (stride 1024), bf16.
// ---------------------------------------------------------------------------
__global__ __launch_bounds__(256) void ctx_k(const void* __restrict__ x2v,
                                             u16* __restrict__ X2C,
                                             const u32* __restrict__ flag)
{
  const bool f32in = (*flag != 0);
  int gid = blockIdx.x * 256 + threadIdx.x;   // 16384*100 threads, 4 ch each
  int bt = gid / 100, oc = gid - bt * 100;
  float a0=0.f, a1=0.f, a2=0.f, a3=0.f;
  if (f32in){
    const float* p = (const float*)x2v + (size_t)bt * 8000 + oc * 4;
    #pragma unroll
    for (int s = 0; s < 20; ++s){
      float4 v = *(const float4*)(p + (size_t)s * 400);
      a0 += v.x; a1 += v.y; a2 += v.z; a3 += v.w;
    }
  } else {
    const u16* p = (const u16*)x2v + (size_t)bt * 8000 + oc * 4;
    #pragma unroll
    for (int s = 0; s < 20; ++s){
      uint2 v = *(const uint2*)(p + (size_t)s * 400);
      a0 += bf2f((u16)(v.x & 0xffff)); a1 += bf2f((u16)(v.x >> 16));
      a2 += bf2f((u16)(v.y & 0xffff)); a3 += bf2f((u16)(v.y >> 16));
    }
  }
  const float sc = 0.05f;  // 1/20
  *(uint2*)(X2C + (size_t)bt * 1024 + oc * 4) =
      make_uint2(pk2(a0*sc, a1*sc), pk2(a2*sc, a3*sc));
}

// ---------------------------------------------------------------------------
// Bidirectional LSTM recurrence. 16 blocks: dir = bid>>3, w = bid&7 owns
// hidden slice [w*32, w*32+32). W_hh fragments in registers. Cross-CU handoff
// via self-validating tagged dwords ((t+1)<<16 | bf16(h)) in agent-scope
// atomics, double-buffered by step parity.
// ---------------------------------------------------------------------------
__global__ __launch_bounds__(256, 1) void lstm_k(
    const u16* __restrict__ XG, const void* __restrict__ whhf, const void* __restrict__ whhb,
    const int* __restrict__ seq_lens, u32* __restrict__ HPUB, u16* __restrict__ HOUT,
    const u32* __restrict__ flag)
{
  const bool f32in = (*flag != 0);
  const int dir = blockIdx.x >> 3, w = blockIdx.x & 7;
  const int tid = threadIdx.x;
  const int lane = tid & 63, wv = tid >> 6;
  const int q = lane >> 4, bl = lane & 15;
  const void* WhhV = dir ? whhb : whhf;

  __shared__ alignas(16) float xga[2][16 * 132];
  __shared__ alignas(16) u16 HT[16 * 264];
  __shared__ u16 hs[16 * 34];

  // Preload A fragments: block rows interleaved j-major (4 gate rows per j)
  s16x8 afr[2][8];
  #pragma unroll
  for (int mt = 0; mt < 2; ++mt){
    int row = wv * 32 + mt * 16 + bl;
    int jloc = row >> 2, gate = row & 3;
    size_t base = (size_t)(gate * 256 + w * 32 + jloc) * 256 + q * 8;
    #pragma unroll
    for (int kt = 0; kt < 8; ++kt){
      if (f32in){
        const float* src = (const float*)WhhV + base + kt * 32;
        s16x8 r;
        #pragma unroll
        for (int i = 0; i < 8; ++i) r[i] = (short)f2bf(src[i]);
        afr[mt][kt] = r;
      } else {
        afr[mt][kt] = *(const s16x8*)((const u16*)WhhV + base + kt * 32);
      }
    }
  }

  const int b_x = tid >> 4;          // batch handled by this thread for staging
  const int sub = tid & 15;
  const int gate_x = sub >> 2;
  const int jj = (sub & 3) * 8;
  const int lenx = seq_lens[b_x];
  const size_t colx = (size_t)(dir * 1024 + gate_x * 256 + w * 32 + jj);
  const int jl0 = wv * 8 + q, jl1 = wv * 8 + 4 + q;
  const int jg0 = w * 32 + jl0, jg1 = w * 32 + jl1;
  u32* HPd = HPUB + dir * 2 * 4096;

  float c0 = 0.f, c1 = 0.f;

  uint4 rx;
  { int rt0 = (dir == 0) ? 0 : (lenx - 1);
    rx = *(const uint4*)(XG + (size_t)(b_x * 1024 + rt0) * 2048 + colx); }

  for (int t = 0; t < 1024; ++t){
    // (1) xg regs -> LDS (parity t&1)
    {
      float* dst = &xga[t & 1][b_x * 132 + gate_x * 32 + jj];
      *(float4*)dst = make_float4(bf2f((u16)(rx.x & 0xffff)), bf2f((u16)(rx.x >> 16)),
                                  bf2f((u16)(rx.y & 0xffff)), bf2f((u16)(rx.y >> 16)));
      *(float4*)(dst + 4) = make_float4(bf2f((u16)(rx.z & 0xffff)), bf2f((u16)(rx.z >> 16)),
                                        bf2f((u16)(rx.w & 0xffff)), bf2f((u16)(rx.w >> 16)));
    }
    // (2) prefetch next step's xg
    if (t + 1 < 1024){
      int tt = t + 1;
      int rt = (dir == 0) ? tt : ((tt < lenx) ? (lenx - 1 - tt) : tt);
      rx = *(const uint4*)(XG + (size_t)(b_x * 1024 + rt) * 2048 + colx);
    }
    // (3) poll full h_{t-1} (tag == t), strip tags into HT ([b][j])
    if (t > 0){
      const u64* src = (const u64*)(HPd + ((t - 1) & 1) * 4096) + tid * 8;
      const u32 tag = (u32)t;
      u64 d[8];
      for (;;){
        bool ok = true;
        #pragma unroll
        for (int u = 0; u < 8; ++u)
          d[u] = __hip_atomic_load(src + u, __ATOMIC_RELAXED, __HIP_MEMORY_SCOPE_AGENT);
        #pragma unroll
        for (int u = 0; u < 8; ++u){
          u32 lo = (u32)d[u], hi = (u32)(d[u] >> 32);
          ok = ok && ((lo >> 16) == tag) && ((hi >> 16) == tag);
        }
        if (ok) break;
      }
      u32 pk[8];
      #pragma unroll
      for (int u = 0; u < 8; ++u){
        u32 lo = (u32)d[u], hi = (u32)(d[u] >> 32);
        pk[u] = (lo & 0xffffu) | (hi << 16);
      }
      u16* hdst = &HT[(tid >> 4) * 264 + (tid & 15) * 16];
      *(uint4*)(hdst)     = make_uint4(pk[0], pk[1], pk[2], pk[3]);
      *(uint4*)(hdst + 8) = make_uint4(pk[4], pk[5], pk[6], pk[7]);
    }
    __syncthreads();
    // (4) matvec (MFMA) + gates + publish
    f32x4 a0 = f32x4{0.f,0.f,0.f,0.f}, a1 = f32x4{0.f,0.f,0.f,0.f};
    if (t > 0){
      #pragma unroll
      for (int kt = 0; kt < 8; ++kt){
        s16x8 bfg = *(const s16x8*)(&HT[bl * 264 + kt * 32 + q * 8]);
        a0 = __builtin_amdgcn_mfma_f32_16x16x32_bf16(afr[0][kt], bfg, a0, 0, 0, 0);
        a1 = __builtin_amdgcn_mfma_f32_16x16x32_bf16(afr[1][kt], bfg, a1, 0, 0, 0);
      }
    }
    const float* xg = &xga[t & 1][bl * 132];
    const u32 tagw = ((u32)(t + 1)) << 16;
    {
      float gi = a0[0] + xg[jl0], gf = a0[1] + xg[32 + jl0];
      float gg = a0[2] + xg[64 + jl0], go = a0[3] + xg[96 + jl0];
      c0 = sigf(gf) * c0 + sigf(gi) * tanhf_(gg);
      u16 hb = f2bf(sigf(go) * tanhf_(c0));
      __hip_atomic_store(HPd + (t & 1) * 4096 + bl * 256 + jg0, tagw | (u32)hb,
                         __ATOMIC_RELAXED, __HIP_MEMORY_SCOPE_AGENT);
      hs[bl * 34 + jl0] = hb;
    }
    {
      float gi = a1[0] + xg[jl1], gf = a1[1] + xg[32 + jl1];
      float gg = a1[2] + xg[64 + jl1], go = a1[3] + xg[96 + jl1];
      c1 = sigf(gf) * c1 + sigf(gi) * tanhf_(gg);
      u16 hb = f2bf(sigf(go) * tanhf_(c1));
      __hip_atomic_store(HPd + (t & 1) * 4096 + bl * 256 + jg1, tagw | (u32)hb,
                         __ATOMIC_RELAXED, __HIP_MEMORY_SCOPE_AGENT);
      hs[bl * 34 + jl1] = hb;
    }
    __syncthreads();
    // (5) coalesced H_out write (backward dir lands at gathered position)
    {
      int jl2 = (tid & 15) * 2;
      u32 lo = hs[b_x * 34 + jl2], hi = hs[b_x * 34 + jl2 + 1];
      int pos = (dir == 0) ? t : ((t < lenx) ? (lenx - 1 - t) : t);
      *(u32*)(HOUT + (size_t)((b_x << 10) + pos) * 512 + dir * 256 + w * 32 + jl2) =
          lo | (hi << 16);
    }
  }
}

// ---------------------------------------------------------------------------
// cm[b,t,c] = cumsum_t(H_out)/(t+1) -> FIN[.,0:512]. Rows t>=len hold garbage
// relative to ref but are zeroed by the final GEMM's mask.
// ---------------------------------------------------------------------------
__global__ __launch_bounds__(256) void cumsum_k(const u16* __restrict__ HOUT, u16* __restrict__ FIN)
{
  int b = blockIdx.x, cc = blockIdx.y;
  int tid = threadIdx.x;
  int c = tid & 31, seg = tid >> 5;      // 32 channels x 8 time-segments of 128
  int ch = cc * 32 + c;
  __shared__ float ss[8][32];

  size_t base = ((size_t)(b * 1024 + seg * 128)) * 512 + ch;
  float s = 0.f;
  #pragma unroll 8
  for (int i = 0; i < 128; ++i) s += bf2f(HOUT[base + (size_t)i * 512]);
  ss[seg][c] = s;
  __syncthreads();
  if (tid < 32){
    float run = 0.f;
    #pragma unroll
    for (int g = 0; g < 8; ++g){ float v = ss[g][tid]; ss[g][tid] = run; run += v; }
  }
  __syncthreads();
  float run = ss[seg][c];
  size_t ob = ((size_t)(b * 1024 + seg * 128)) * 1024 + cc * 32 + c;
  #pragma unroll 8
  for (int i = 0; i < 128; ++i){
    run += bf2f(HOUT[base + (size_t)i * 512]);
    int t = seg * 128 + i;
    FIN[ob + (size_t)i * 1024] = f2bf(run * rcpf_((float)(t + 1)));
  }
}

// ---------------------------------------------------------------------------
extern "C" void kernel_launch(void* const* d_in, const int* in_sizes, int n_in,
                              void* d_out, int out_size, void* d_ws, size_t ws_size,
                              hipStream_t stream)
{
  (void)in_sizes; (void)n_in; (void)out_size; (void)ws_size;
  const int* lens = (const int*)d_in[2];

  char* ws = (char*)d_ws;
  u16* XG   = (u16*)(ws);                    // 16384 x 2048 bf16 = 64 MiB
  u16* FIN  = (u16*)(ws + 67108864);         // 16384 x 1024 bf16 (X2C | cm | x2h)
  u16* HOUT = (u16*)(ws + 100663296);        // 16384 x 512 bf16 = 16 MiB
  u32* HPUB = (u32*)(ws + 117440512);        // 2 dir x 2 parity x 16 x 256 dwords
  u32* FLAG = (u32*)(ws + 117506048);        // dtype flag (1 = f32 inputs)

  // 0. runtime dtype detection
  sniff_k<<<1, 64, 0, stream>>>((const u32*)d_in[0], FLAG);
  // 1. XG = x1 @ [w_ih_f; w_ih_b]^T + (b_ih + b_hh)
  gemm_k<0><<<dim3(128, 16), 256, 0, stream>>>(d_in[0], d_in[7], d_in[11],
      d_in[9], d_in[10], d_in[13], d_in[14], XG, nullptr, FLAG);
  // 2. x2ctx = mean_s x2  -> FIN[:,0:400]
  ctx_k<<<6400, 256, 0, stream>>>(d_in[1], FIN, FLAG);
  // 3. x2h = X2C @ mlp_mha_w^T + b  -> FIN[:,512:1024]
  gemm_k<1><<<dim3(128, 4), 256, 0, stream>>>(FIN, d_in[5], nullptr,
      d_in[6], nullptr, nullptr, nullptr, FIN, nullptr, FLAG);
  // 4. bidirectional LSTM recurrence
  lstm_k<<<16, 256, 0, stream>>>(XG, d_in[8], d_in[12], lens, HPUB, HOUT, FLAG);
  // 5. cm -> FIN[:,0:512]
  cumsum_k<<<dim3(16, 16), 256, 0, stream>>>(HOUT, FIN);
  // 6. out = FIN @ mlp_w^T + mlp_b, masked
  gemm_k<2><<<dim3(128, 4), 256, 0, stream>>>(FIN, d_in[15], nullptr,
      d_in[16], nullptr, nullptr, nullptr, d_out, lens, FLAG);
}